// Round 10
// baseline (1127.341 us; speedup 1.0000x reference)
//
#include <hip/hip_runtime.h>
#include <hip/hip_bf16.h>
#include <cstdint>
#include <cstddef>

#define D_MODEL 1024
#define FF_DIM  4096
#define NEXP    8
#define TOK     8192
#define CAP     2560          // ceil(1.25 * 8192*2 / 8)
#define ECAP    (NEXP*CAP)    // 20480
#define LSCALE  2.0f          // lora_alpha / rank = 4/2
#define SA_BYTE 124           // activations stored x8  -> scale 2^-3
#define SB_BYTE 122           // weights stored x32     -> scale 2^-5

typedef __attribute__((ext_vector_type(8))) int   int32x8;
typedef __attribute__((ext_vector_type(4))) float f32x4;
typedef __attribute__((ext_vector_type(2))) float f32x2;

__device__ __forceinline__ float gelu_tanh(float x){
  float u = 0.7978845608028654f * (x + 0.044715f * x * x * x);
  float e = __expf(2.0f * u);
  float t = 1.0f - 2.0f / (e + 1.0f);
  return 0.5f * x * (1.0f + t);
}

// ---- fused prep: blocks 0..2047 = gating (+zero-init), 2048..4095 = weight quant ----
__global__ void prep_kernel(const float* __restrict__ x, const float* __restrict__ Wg,
                            int* __restrict__ exp_flat, float* __restrict__ g_flat,
                            float* __restrict__ pooled, float* __restrict__ wslot,
                            const float* __restrict__ W1, const float* __restrict__ W2,
                            uint8_t* __restrict__ W1q, uint8_t* __restrict__ W2q)
{
  __shared__ float tile[64][65];
  int bx = blockIdx.x;
  int tid = threadIdx.x;
  if (bx < 2048){
    int gid = bx * 256 + tid;
    if (gid < 4*D_MODEL) pooled[gid] = 0.f;
    else if (gid < 4*D_MODEL + ECAP) wslot[gid - 4*D_MODEL] = 0.f;
    int lane = tid & 63;
    int wave = tid >> 6;
    int t = bx * 4 + wave;
    const float4* xv = (const float4*)(x + (size_t)t * D_MODEL);
    float acc[8];
#pragma unroll
    for (int e = 0; e < 8; e++) acc[e] = 0.f;
#pragma unroll
    for (int i = 0; i < 4; i++){
      int i4 = lane + i*64;
      float4 v = xv[i4];
#pragma unroll
      for (int k = 0; k < 4; k++){
        float xs = (&v.x)[k];
        const float4* wr = (const float4*)(Wg + (size_t)(i4*4 + k) * 8);
        float4 w0 = wr[0], w1 = wr[1];
        acc[0] += xs*w0.x; acc[1] += xs*w0.y; acc[2] += xs*w0.z; acc[3] += xs*w0.w;
        acc[4] += xs*w1.x; acc[5] += xs*w1.y; acc[6] += xs*w1.z; acc[7] += xs*w1.w;
      }
    }
#pragma unroll
    for (int off = 32; off > 0; off >>= 1){
#pragma unroll
      for (int e = 0; e < 8; e++) acc[e] += __shfl_down(acc[e], off);
    }
    if (lane == 0){
      float m0 = acc[0]; int e0 = 0;
#pragma unroll
      for (int e = 1; e < 8; e++) if (acc[e] > m0){ m0 = acc[e]; e0 = e; }
      float m1 = -3.4e38f; int e1 = 0;
#pragma unroll
      for (int e = 0; e < 8; e++) if (e != e0 && acc[e] > m1){ m1 = acc[e]; e1 = e; }
      float z = __expf(m1 - m0);
      float inv = 1.f / (1.f + z);
      exp_flat[t]       = e0;
      exp_flat[TOK + t] = e1;
      g_flat[t]         = inv;
      g_flat[TOK + t]   = z * inv;
    }
  } else {
    int b = bx - 2048;
    int z = b >> 10; b &= 1023;
    int bxx = b & 15, byy = b >> 4;
    const float* src; uint8_t* dst; int srcld, dstld, a0, b0;
    if (z == 0){ src = W1; dst = W1q; srcld = FF_DIM; dstld = D_MODEL; a0 = bxx*64; b0 = byy*64; }
    else       { src = W2; dst = W2q; srcld = D_MODEL; dstld = FF_DIM; a0 = byy*64; b0 = bxx*64; }
    int r  = tid >> 4;
    int c4 = (tid & 15) * 4;
#pragma unroll
    for (int i = 0; i < 4; i++){
      int al = r + i*16;
      float4 v = *(const float4*)(src + (size_t)(a0 + al) * srcld + b0 + c4);
      tile[al][c4+0] = v.x; tile[al][c4+1] = v.y; tile[al][c4+2] = v.z; tile[al][c4+3] = v.w;
    }
    __syncthreads();
#pragma unroll
    for (int i = 0; i < 4; i++){
      int bl = r + i*16;
      int bb = b0 + bl;
      int pk = __builtin_amdgcn_cvt_pk_fp8_f32(32.f*tile[c4+0][bl], 32.f*tile[c4+1][bl], 0, false);
      pk     = __builtin_amdgcn_cvt_pk_fp8_f32(32.f*tile[c4+2][bl], 32.f*tile[c4+3][bl], pk, true);
      *(int*)(dst + (size_t)bb * dstld + a0 + c4) = pk;
    }
  }
}

// ------- routing, parallel: exact slot-major cumulative positions ------------
__global__ __launch_bounds__(1024) void route_all(const int* __restrict__ exp_flat,
                                                  const float* __restrict__ g_flat,
                                                  int* __restrict__ slotidx,
                                                  float* __restrict__ wcomb,
                                                  int* __restrict__ fillc)
{
  __shared__ uint8_t rnk[16384];
  __shared__ uint8_t eexp[16384];
  __shared__ int     cnt[256*8];
  __shared__ int     grpoff[64];
  int tid = threadIdx.x;
  int lane = tid & 63, wv = tid >> 6;
  unsigned long long ltmask = (1ull << lane) - 1ull;
  for (int c = wv; c < 256; c += 16){
    int j = c*64 + lane;
    int e = exp_flat[j];
    eexp[j] = (uint8_t)e;
    int r = 0, myc = 0;
#pragma unroll
    for (int q = 0; q < 8; q++){
      unsigned long long m = __ballot(e == q);
      if (e == q) r = __popcll(m & ltmask);
      if (lane == q) myc = __popcll(m);
    }
    rnk[j] = (uint8_t)r;
    if (lane < 8) cnt[c*8 + lane] = myc;
  }
  __syncthreads();
  if (wv == 0){
    int e = lane & 7, g = lane >> 3;
    int run = 0;
    for (int c = g*32; c < g*32 + 32; c++){
      int v = cnt[c*8 + e];
      cnt[c*8 + e] = run;
      run += v;
    }
    int offs = 0, tot = 0;
#pragma unroll
    for (int gg = 0; gg < 8; gg++){
      int v = __shfl(run, gg*8 + e);
      if (gg < g) offs += v;
      tot += v;
    }
    grpoff[lane] = offs;
    if (g == 0) fillc[e] = tot < CAP ? tot : CAP;
  }
  __syncthreads();
  for (int j = tid; j < 16384; j += 1024){
    int e = eexp[j];
    int c = j >> 6;
    int pos = cnt[c*8 + e] + grpoff[(c >> 5)*8 + e] + rnk[j];
    bool keep = pos < CAP;
    slotidx[j] = e*CAP + (keep ? pos : (CAP-1));
    wcomb[j]   = keep ? g_flat[j] : 0.f;
  }
}

// -------- dispatch: scatter tokens -> fp8 buffer (x8) + fused U1 = x.A1 ------
__global__ void dispatch_kernel(const float* __restrict__ x, const int* __restrict__ slotidx,
                                const float* __restrict__ wcomb, uint8_t* __restrict__ dispA,
                                float* __restrict__ wslot, int* __restrict__ tbat,
                                const float* __restrict__ A1, float* __restrict__ U1)
{
  int j = blockIdx.x;
  float w = wcomb[j];
  if (w == 0.f) return;
  int t = j & (TOK - 1);
  int slot = slotidx[j];
  int e = slot / CAP;
  int i = threadIdx.x;
  const float4* src = (const float4*)(x + (size_t)t * D_MODEL);
  float4 a = src[2*i], b = src[2*i+1];
  int p0 = __builtin_amdgcn_cvt_pk_fp8_f32(8.f*a.x, 8.f*a.y, 0, false);
  p0     = __builtin_amdgcn_cvt_pk_fp8_f32(8.f*a.z, 8.f*a.w, p0, true);
  int p1 = __builtin_amdgcn_cvt_pk_fp8_f32(8.f*b.x, 8.f*b.y, 0, false);
  p1     = __builtin_amdgcn_cvt_pk_fp8_f32(8.f*b.z, 8.f*b.w, p1, true);
  int2 o; o.x = p0; o.y = p1;
  *(int2*)(dispA + (size_t)slot * D_MODEL + i*8) = o;
  const float2* Av = (const float2*)(A1 + (size_t)e * D_MODEL * 2);
  int d0 = i*8;
  float xs[8] = {a.x,a.y,a.z,a.w,b.x,b.y,b.z,b.w};
  float pa = 0.f, pb = 0.f;
#pragma unroll
  for (int k = 0; k < 8; k++){
    float2 w2 = Av[d0 + k];
    pa += xs[k]*w2.x; pb += xs[k]*w2.y;
  }
#pragma unroll
  for (int off = 32; off > 0; off >>= 1){
    pa += __shfl_down(pa, off);
    pb += __shfl_down(pb, off);
  }
  __shared__ float red[4];
  int lane = i & 63, wv = i >> 6;
  if (lane == 0){ red[wv*2] = pa; red[wv*2+1] = pb; }
  __syncthreads();
  if (i == 0){
    U1[slot*2+0] = red[0] + red[2];
    U1[slot*2+1] = red[1] + red[3];
    wslot[slot] = w; tbat[slot] = t >> 11;
  }
}

// ------- LoRA rank-2 projection: U[slot][r] = (X_row/8) . A_e[:,r] -----------
__global__ void lora_u(const uint8_t* __restrict__ X, const float* __restrict__ Aw,
                       float* __restrict__ U, int Kdim)
{
  int lane = threadIdx.x & 63;
  int wv   = threadIdx.x >> 6;
  int slot = blockIdx.x * 4 + wv;
  int e = slot / CAP;
  const int4*   row = (const int4*)(X + (size_t)slot * Kdim);
  const float2* Av  = (const float2*)(Aw + (size_t)e * Kdim * 2);
  float a0 = 0.f, a1 = 0.f;
  int n16 = Kdim >> 4;
  for (int i = lane; i < n16; i += 64){
    int4 v = row[i];
    int d = i * 16;
#pragma unroll
    for (int c = 0; c < 4; c++){
      int w = (&v.x)[c];
      f32x2 f01 = __builtin_amdgcn_cvt_pk_f32_fp8(w, false);
      f32x2 f23 = __builtin_amdgcn_cvt_pk_f32_fp8(w, true);
      int dd = d + c*4;
      float2 w0 = Av[dd], w1 = Av[dd+1], w2 = Av[dd+2], w3 = Av[dd+3];
      a0 += f01.x*w0.x + f01.y*w1.x + f23.x*w2.x + f23.y*w3.x;
      a1 += f01.x*w0.y + f01.y*w1.y + f23.x*w2.y + f23.y*w3.y;
    }
  }
#pragma unroll
  for (int off = 32; off > 0; off >>= 1){
    a0 += __shfl_down(a0, off);
    a1 += __shfl_down(a1, off);
  }
  if (lane == 0){ U[slot*2] = a0 * 0.125f; U[slot*2+1] = a1 * 0.125f; }
}

// ------ MX-fp8 GEMM, ALL-REGISTER barrier-free K-loop ------------------------
// No LDS for operands, no __syncthreads in the loop: each wave loads its own
// A/B fragments (dense 16-row x 128B regions) straight to registers, register-
// double-buffered one window ahead. Without a barrier there is no vmcnt(0)
// drain — the compiler waits only on the current window (vmcnt(N)), so the
// next window's 12 loads stay in flight through the full MFMA phase.
// Block tile 64x128: 4 waves as 2(wm) x 2(wn), each wave 32 rows x 64 cols.
template<bool GELU, bool COMBINE>
__global__ __launch_bounds__(256) void gemm_mx(const uint8_t* __restrict__ A,
                                               const uint8_t* __restrict__ Bt,
                                               uint8_t* __restrict__ Cb,
                                               int K, int N, const int* __restrict__ fillc,
                                               const float* __restrict__ U,
                                               const float* __restrict__ Bl,
                                               const float* __restrict__ wslot,
                                               const int* __restrict__ tbat,
                                               float* __restrict__ pooled)
{
  int e = blockIdx.x / 40;                       // CAP/64 = 40 row tiles per expert
  if ((blockIdx.x % 40) * 64 >= fillc[e]) return;
  int row0 = blockIdx.x * 64;
  int col0 = blockIdx.y * 128;

  __shared__ float part[COMBINE ? 512 : 4];      // epilogue only

  int tid  = threadIdx.x;
  int lane = tid & 63;
  int wave = tid >> 6;
  int wm = wave & 1, wn = wave >> 1;

  int rb = lane & 15;
  int q  = lane >> 4;                  // k-group: bytes q*32..q*32+31

  const uint8_t* gA = A  + (size_t)(row0 + wm*32 + rb) * K + q*32;
  const uint8_t* gB = Bt + (size_t)(col0 + wn*64 + rb) * K + q*32;

  f32x4 acc[2][4];
#pragma unroll
  for (int i = 0; i < 2; i++)
#pragma unroll
    for (int j = 0; j < 4; j++)
      acc[i][j] = (f32x4){0.f, 0.f, 0.f, 0.f};

  auto loadW = [&](int k0, int32x8* a, int32x8* b){
#pragma unroll
    for (int mt = 0; mt < 2; mt++){
      const uint8_t* p = gA + (size_t)mt*16*K + k0;
      int4 lo = *(const int4*)p;
      int4 hi = *(const int4*)(p + 16);
      int32x8 v; v[0]=lo.x; v[1]=lo.y; v[2]=lo.z; v[3]=lo.w;
                 v[4]=hi.x; v[5]=hi.y; v[6]=hi.z; v[7]=hi.w;
      a[mt] = v;
    }
#pragma unroll
    for (int nt = 0; nt < 4; nt++){
      const uint8_t* p = gB + (size_t)nt*16*K + k0;
      int4 lo = *(const int4*)p;
      int4 hi = *(const int4*)(p + 16);
      int32x8 v; v[0]=lo.x; v[1]=lo.y; v[2]=lo.z; v[3]=lo.w;
                 v[4]=hi.x; v[5]=hi.y; v[6]=hi.z; v[7]=hi.w;
      b[nt] = v;
    }
  };
  auto compute = [&](const int32x8* a, const int32x8* b){
#pragma unroll
    for (int mt = 0; mt < 2; mt++)
#pragma unroll
      for (int nt = 0; nt < 4; nt++)
        acc[mt][nt] = __builtin_amdgcn_mfma_scale_f32_16x16x128_f8f6f4(
            a[mt], b[nt], acc[mt][nt], 0, 0, 0, SA_BYTE, 0, SB_BYTE);
  };

  int32x8 a0[2], b0[4], a1[2], b1[4];
  loadW(0, a0, b0);
  int NI = K >> 7;                     // 8 (GEMM1) or 32 (GEMM2), always even
  for (int p = 0; p < NI; p += 2){
    if (p+1 < NI) loadW((p+1) << 7, a1, b1);
    compute(a0, b0);
    if (p+2 < NI) loadW((p+2) << 7, a0, b0);
    compute(a1, b1);
  }

  // LoRA B factors for this lane's 4 columns
  float b0c[4], b1c[4];
#pragma unroll
  for (int nt = 0; nt < 4; nt++){
    int col = col0 + wn*64 + rb + nt*16;
    b0c[nt] = Bl[(e*2+0)*N + col];
    b1c[nt] = Bl[(e*2+1)*N + col];
  }

  if (COMBINE){
    part[tid] = 0.f; part[tid + 256] = 0.f;
    __syncthreads();
  }

#pragma unroll
  for (int mt = 0; mt < 2; mt++){
#pragma unroll
    for (int r = 0; r < 4; r++){
      int row = row0 + wm*32 + mt*16 + q*4 + r;
      float2 u = *(const float2*)(U + row*2);
      float wv = 0.f; int tb = 0;
      if (COMBINE){ wv = wslot[row]; tb = tbat[row]; }
      size_t base = (size_t)row * N + col0 + wn*64 + rb;
#pragma unroll
      for (int nt = 0; nt < 4; nt++){
        float v = acc[mt][nt][r] + LSCALE*(u.x*b0c[nt] + u.y*b1c[nt]);
        if (GELU){
          v = gelu_tanh(v);
          int pk = __builtin_amdgcn_cvt_pk_fp8_f32(8.f*v, 0.f, 0, false);
          Cb[base + nt*16] = (uint8_t)(pk & 0xFF);
        }
        if (COMBINE){
          if (wv != 0.f) atomicAdd(&part[tb*128 + wn*64 + rb + nt*16], wv*v);
        }
      }
    }
  }

  if (COMBINE){
    __syncthreads();
#pragma unroll
    for (int idx = tid; idx < 512; idx += 256){
      float pv = part[idx];
      if (pv != 0.f) atomicAdd(pooled + (size_t)(idx >> 7) * D_MODEL + col0 + (idx & 127), pv);
    }
  }
}

// ---------------- head: out[b][c] = mean_pool . Wh + bh ----------------------
__global__ void head_kernel(const float* __restrict__ pooled, const float* __restrict__ Wh,
                            const float* __restrict__ bh, float* __restrict__ out)
{
  int lane = threadIdx.x & 63;
  int wave = threadIdx.x >> 6;
  int b = wave >> 1, c = wave & 1;
  float s = 0.f;
#pragma unroll
  for (int i = 0; i < 16; i++){
    int d = lane + i*64;
    s += pooled[(size_t)b * D_MODEL + d] * Wh[d*2 + c];
  }
#pragma unroll
  for (int off = 32; off > 0; off >>= 1) s += __shfl_down(s, off);
  if (lane == 0) out[b*2 + c] = s * (1.0f/2048.0f) + bh[c];
}

// ---------------- launch ------------------------------------------------------
extern "C" void kernel_launch(void* const* d_in, const int* in_sizes, int n_in,
                              void* d_out, int out_size, void* d_ws, size_t ws_size,
                              hipStream_t stream)
{
  const float* x  = (const float*)d_in[0];
  const float* Wg = (const float*)d_in[1];
  const float* W1 = (const float*)d_in[2];
  const float* W2 = (const float*)d_in[3];
  const float* A1 = (const float*)d_in[4];
  const float* B1 = (const float*)d_in[5];
  const float* A2 = (const float*)d_in[6];
  const float* B2 = (const float*)d_in[7];
  const float* Wh = (const float*)d_in[8];
  const float* bh = (const float*)d_in[9];
  float* out = (float*)d_out;

  char* p = (char*)d_ws;
  auto alloc = [&](size_t bytes){
    char* r = p;
    p += (bytes + 255) & ~(size_t)255;
    return (void*)r;
  };
  uint8_t* W1q   = (uint8_t*)alloc((size_t)FF_DIM*D_MODEL);     // 4 MB
  uint8_t* W2q   = (uint8_t*)alloc((size_t)D_MODEL*FF_DIM);     // 4 MB
  uint8_t* dispA = (uint8_t*)alloc((size_t)ECAP*D_MODEL);       // 20 MB
  uint8_t* H     = (uint8_t*)alloc((size_t)ECAP*FF_DIM);        // 80 MB
  float* U1       = (float*)alloc((size_t)ECAP*2*4);
  float* U2       = (float*)alloc((size_t)ECAP*2*4);
  float* wslot    = (float*)alloc((size_t)ECAP*4);
  int*   tbat     = (int*)  alloc((size_t)ECAP*4);
  int*   exp_flat = (int*)  alloc((size_t)2*TOK*4);
  float* g_flat   = (float*)alloc((size_t)2*TOK*4);
  int*   slotidx  = (int*)  alloc((size_t)2*TOK*4);
  float* wcomb    = (float*)alloc((size_t)2*TOK*4);
  int*   fillc    = (int*)  alloc(256);
  float* pooled   = (float*)alloc((size_t)4*D_MODEL*4);

  prep_kernel<<<4096, 256, 0, stream>>>(x, Wg, exp_flat, g_flat, pooled, wslot,
                                        W1, W2, W1q, W2q);
  route_all<<<1, 1024, 0, stream>>>(exp_flat, g_flat, slotidx, wcomb, fillc);
  dispatch_kernel<<<2*TOK, 128, 0, stream>>>(x, slotidx, wcomb, dispA, wslot, tbat, A1, U1);
  gemm_mx<true, false><<<dim3(320,32), 256, 0, stream>>>(dispA, W1q, H, D_MODEL, FF_DIM,
                                                         fillc, U1, B1, nullptr, nullptr, nullptr);
  lora_u<<<5120, 256, 0, stream>>>(H, A2, U2, FF_DIM);
  gemm_mx<false, true><<<dim3(320,8), 256, 0, stream>>>(H, W2q, nullptr, FF_DIM, D_MODEL,
                                                        fillc, U2, B2, wslot, tbat, pooled);
  head_kernel<<<1, 512, 0, stream>>>(pooled, Wh, bh, out);
}

// Round 11
// 572.059 us; speedup vs baseline: 1.9707x; 1.9707x over previous
//
#include <hip/hip_runtime.h>
#include <hip/hip_bf16.h>
#include <cstdint>
#include <cstddef>

#define D_MODEL 1024
#define FF_DIM  4096
#define NEXP    8
#define TOK     8192
#define CAP     2560          // ceil(1.25 * 8192*2 / 8)
#define ECAP    (NEXP*CAP)    // 20480
#define LSCALE  2.0f          // lora_alpha / rank = 4/2
#define SA_BYTE 124           // activations stored x8  -> scale 2^-3
#define SB_BYTE 122           // weights stored x32     -> scale 2^-5

typedef __attribute__((ext_vector_type(8))) int   int32x8;
typedef __attribute__((ext_vector_type(4))) float f32x4;
typedef __attribute__((ext_vector_type(2))) float f32x2;

__device__ __forceinline__ void gload16(const void* g, void* l){
  __builtin_amdgcn_global_load_lds((const __attribute__((address_space(1))) void*)g,
                                   (__attribute__((address_space(3))) void*)l, 16, 0, 0);
}
__device__ __forceinline__ float gelu_tanh(float x){
  float u = 0.7978845608028654f * (x + 0.044715f * x * x * x);
  float e = __expf(2.0f * u);
  float t = 1.0f - 2.0f / (e + 1.0f);
  return 0.5f * x * (1.0f + t);
}

// ---- fused prep: blocks 0..2047 = gating (+zero-init), 2048..4095 = weight quant ----
__global__ void prep_kernel(const float* __restrict__ x, const float* __restrict__ Wg,
                            int* __restrict__ exp_flat, float* __restrict__ g_flat,
                            float* __restrict__ pooled, float* __restrict__ wslot,
                            const float* __restrict__ W1, const float* __restrict__ W2,
                            uint8_t* __restrict__ W1q, uint8_t* __restrict__ W2q)
{
  __shared__ float tile[64][65];
  int bx = blockIdx.x;
  int tid = threadIdx.x;
  if (bx < 2048){
    int gid = bx * 256 + tid;
    if (gid < 4*D_MODEL) pooled[gid] = 0.f;
    else if (gid < 4*D_MODEL + ECAP) wslot[gid - 4*D_MODEL] = 0.f;
    int lane = tid & 63;
    int wave = tid >> 6;
    int t = bx * 4 + wave;
    const float4* xv = (const float4*)(x + (size_t)t * D_MODEL);
    float acc[8];
#pragma unroll
    for (int e = 0; e < 8; e++) acc[e] = 0.f;
#pragma unroll
    for (int i = 0; i < 4; i++){
      int i4 = lane + i*64;
      float4 v = xv[i4];
#pragma unroll
      for (int k = 0; k < 4; k++){
        float xs = (&v.x)[k];
        const float4* wr = (const float4*)(Wg + (size_t)(i4*4 + k) * 8);
        float4 w0 = wr[0], w1 = wr[1];
        acc[0] += xs*w0.x; acc[1] += xs*w0.y; acc[2] += xs*w0.z; acc[3] += xs*w0.w;
        acc[4] += xs*w1.x; acc[5] += xs*w1.y; acc[6] += xs*w1.z; acc[7] += xs*w1.w;
      }
    }
#pragma unroll
    for (int off = 32; off > 0; off >>= 1){
#pragma unroll
      for (int e = 0; e < 8; e++) acc[e] += __shfl_down(acc[e], off);
    }
    if (lane == 0){
      float m0 = acc[0]; int e0 = 0;
#pragma unroll
      for (int e = 1; e < 8; e++) if (acc[e] > m0){ m0 = acc[e]; e0 = e; }
      float m1 = -3.4e38f; int e1 = 0;
#pragma unroll
      for (int e = 0; e < 8; e++) if (e != e0 && acc[e] > m1){ m1 = acc[e]; e1 = e; }
      float z = __expf(m1 - m0);
      float inv = 1.f / (1.f + z);
      exp_flat[t]       = e0;
      exp_flat[TOK + t] = e1;
      g_flat[t]         = inv;
      g_flat[TOK + t]   = z * inv;
    }
  } else {
    int b = bx - 2048;
    int z = b >> 10; b &= 1023;
    int bxx = b & 15, byy = b >> 4;
    const float* src; uint8_t* dst; int srcld, dstld, a0, b0;
    if (z == 0){ src = W1; dst = W1q; srcld = FF_DIM; dstld = D_MODEL; a0 = bxx*64; b0 = byy*64; }
    else       { src = W2; dst = W2q; srcld = D_MODEL; dstld = FF_DIM; a0 = byy*64; b0 = bxx*64; }
    int r  = tid >> 4;
    int c4 = (tid & 15) * 4;
#pragma unroll
    for (int i = 0; i < 4; i++){
      int al = r + i*16;
      float4 v = *(const float4*)(src + (size_t)(a0 + al) * srcld + b0 + c4);
      tile[al][c4+0] = v.x; tile[al][c4+1] = v.y; tile[al][c4+2] = v.z; tile[al][c4+3] = v.w;
    }
    __syncthreads();
#pragma unroll
    for (int i = 0; i < 4; i++){
      int bl = r + i*16;
      int bb = b0 + bl;
      int pk = __builtin_amdgcn_cvt_pk_fp8_f32(32.f*tile[c4+0][bl], 32.f*tile[c4+1][bl], 0, false);
      pk     = __builtin_amdgcn_cvt_pk_fp8_f32(32.f*tile[c4+2][bl], 32.f*tile[c4+3][bl], pk, true);
      *(int*)(dst + (size_t)bb * dstld + a0 + c4) = pk;
    }
  }
}

// ------- routing, parallel: exact slot-major cumulative positions ------------
__global__ __launch_bounds__(1024) void route_all(const int* __restrict__ exp_flat,
                                                  const float* __restrict__ g_flat,
                                                  int* __restrict__ slotidx,
                                                  float* __restrict__ wcomb,
                                                  int* __restrict__ fillc)
{
  __shared__ uint8_t rnk[16384];
  __shared__ uint8_t eexp[16384];
  __shared__ int     cnt[256*8];
  __shared__ int     grpoff[64];
  int tid = threadIdx.x;
  int lane = tid & 63, wv = tid >> 6;
  unsigned long long ltmask = (1ull << lane) - 1ull;
  for (int c = wv; c < 256; c += 16){
    int j = c*64 + lane;
    int e = exp_flat[j];
    eexp[j] = (uint8_t)e;
    int r = 0, myc = 0;
#pragma unroll
    for (int q = 0; q < 8; q++){
      unsigned long long m = __ballot(e == q);
      if (e == q) r = __popcll(m & ltmask);
      if (lane == q) myc = __popcll(m);
    }
    rnk[j] = (uint8_t)r;
    if (lane < 8) cnt[c*8 + lane] = myc;
  }
  __syncthreads();
  if (wv == 0){
    int e = lane & 7, g = lane >> 3;
    int run = 0;
    for (int c = g*32; c < g*32 + 32; c++){
      int v = cnt[c*8 + e];
      cnt[c*8 + e] = run;
      run += v;
    }
    int offs = 0, tot = 0;
#pragma unroll
    for (int gg = 0; gg < 8; gg++){
      int v = __shfl(run, gg*8 + e);
      if (gg < g) offs += v;
      tot += v;
    }
    grpoff[lane] = offs;
    if (g == 0) fillc[e] = tot < CAP ? tot : CAP;
  }
  __syncthreads();
  for (int j = tid; j < 16384; j += 1024){
    int e = eexp[j];
    int c = j >> 6;
    int pos = cnt[c*8 + e] + grpoff[(c >> 5)*8 + e] + rnk[j];
    bool keep = pos < CAP;
    slotidx[j] = e*CAP + (keep ? pos : (CAP-1));
    wcomb[j]   = keep ? g_flat[j] : 0.f;
  }
}

// -------- dispatch: scatter tokens -> fp8 buffer (x8) + fused U1 = x.A1 ------
__global__ void dispatch_kernel(const float* __restrict__ x, const int* __restrict__ slotidx,
                                const float* __restrict__ wcomb, uint8_t* __restrict__ dispA,
                                float* __restrict__ wslot, int* __restrict__ tbat,
                                const float* __restrict__ A1, float* __restrict__ U1)
{
  int j = blockIdx.x;
  float w = wcomb[j];
  if (w == 0.f) return;
  int t = j & (TOK - 1);
  int slot = slotidx[j];
  int e = slot / CAP;
  int i = threadIdx.x;
  const float4* src = (const float4*)(x + (size_t)t * D_MODEL);
  float4 a = src[2*i], b = src[2*i+1];
  int p0 = __builtin_amdgcn_cvt_pk_fp8_f32(8.f*a.x, 8.f*a.y, 0, false);
  p0     = __builtin_amdgcn_cvt_pk_fp8_f32(8.f*a.z, 8.f*a.w, p0, true);
  int p1 = __builtin_amdgcn_cvt_pk_fp8_f32(8.f*b.x, 8.f*b.y, 0, false);
  p1     = __builtin_amdgcn_cvt_pk_fp8_f32(8.f*b.z, 8.f*b.w, p1, true);
  int2 o; o.x = p0; o.y = p1;
  *(int2*)(dispA + (size_t)slot * D_MODEL + i*8) = o;
  const float2* Av = (const float2*)(A1 + (size_t)e * D_MODEL * 2);
  int d0 = i*8;
  float xs[8] = {a.x,a.y,a.z,a.w,b.x,b.y,b.z,b.w};
  float pa = 0.f, pb = 0.f;
#pragma unroll
  for (int k = 0; k < 8; k++){
    float2 w2 = Av[d0 + k];
    pa += xs[k]*w2.x; pb += xs[k]*w2.y;
  }
#pragma unroll
  for (int off = 32; off > 0; off >>= 1){
    pa += __shfl_down(pa, off);
    pb += __shfl_down(pb, off);
  }
  __shared__ float red[4];
  int lane = i & 63, wv = i >> 6;
  if (lane == 0){ red[wv*2] = pa; red[wv*2+1] = pb; }
  __syncthreads();
  if (i == 0){
    U1[slot*2+0] = red[0] + red[2];
    U1[slot*2+1] = red[1] + red[3];
    wslot[slot] = w; tbat[slot] = t >> 11;
  }
}

// ------- LoRA rank-2 projection: U[slot][r] = (X_row/8) . A_e[:,r] -----------
__global__ void lora_u(const uint8_t* __restrict__ X, const float* __restrict__ Aw,
                       float* __restrict__ U, int Kdim)
{
  int lane = threadIdx.x & 63;
  int wv   = threadIdx.x >> 6;
  int slot = blockIdx.x * 4 + wv;
  int e = slot / CAP;
  const int4*   row = (const int4*)(X + (size_t)slot * Kdim);
  const float2* Av  = (const float2*)(Aw + (size_t)e * Kdim * 2);
  float a0 = 0.f, a1 = 0.f;
  int n16 = Kdim >> 4;
  for (int i = lane; i < n16; i += 64){
    int4 v = row[i];
    int d = i * 16;
#pragma unroll
    for (int c = 0; c < 4; c++){
      int w = (&v.x)[c];
      f32x2 f01 = __builtin_amdgcn_cvt_pk_f32_fp8(w, false);
      f32x2 f23 = __builtin_amdgcn_cvt_pk_f32_fp8(w, true);
      int dd = d + c*4;
      float2 w0 = Av[dd], w1 = Av[dd+1], w2 = Av[dd+2], w3 = Av[dd+3];
      a0 += f01.x*w0.x + f01.y*w1.x + f23.x*w2.x + f23.y*w3.x;
      a1 += f01.x*w0.y + f01.y*w1.y + f23.x*w2.y + f23.y*w3.y;
    }
  }
#pragma unroll
  for (int off = 32; off > 0; off >>= 1){
    a0 += __shfl_down(a0, off);
    a1 += __shfl_down(a1, off);
  }
  if (lane == 0){ U[slot*2] = a0 * 0.125f; U[slot*2+1] = a1 * 0.125f; }
}

// ------ MX-fp8 GEMM, 64x128 tile, BOTH-LDS single-barrier DOUBLE BUFFER ------
// r3's both-through-LDS reuse + dbuf: each window's global_load_lds DMA is
// issued right after the sync and has a full compute phase (~500 cy) to land
// before the NEXT sync drains it (vs r3's zero head start). One barrier per
// window. Race-free: the sync before stage(p+1) guarantees all ds_reads of
// that buffer (compute p-1) retired before DMA overwrites it.
template<bool GELU, bool COMBINE>
__global__ __launch_bounds__(256) void gemm_mx(const uint8_t* __restrict__ A,
                                               const uint8_t* __restrict__ Bt,
                                               uint8_t* __restrict__ Cb,
                                               int K, int N, const int* __restrict__ fillc,
                                               const float* __restrict__ U,
                                               const float* __restrict__ Bl,
                                               const float* __restrict__ wslot,
                                               const int* __restrict__ tbat,
                                               float* __restrict__ pooled)
{
  int e = blockIdx.x / 40;                       // CAP/64 = 40 row tiles per expert
  if ((blockIdx.x % 40) * 64 >= fillc[e]) return;
  int row0 = blockIdx.x * 64;
  int col0 = blockIdx.y * 128;

  __shared__ __align__(16) uint8_t As0[64*128];   // 8 KB x2
  __shared__ __align__(16) uint8_t As1[64*128];
  __shared__ __align__(16) uint8_t Bs0[128*128];  // 16 KB x2  (total 48 KB)
  __shared__ __align__(16) uint8_t Bs1[128*128];
  __shared__ float part[COMBINE ? 512 : 4];

  int tid  = threadIdx.x;
  int lane = tid & 63;
  int wave = tid >> 6;
  int wm = wave & 1, wn = wave >> 1;

  int r8 = lane >> 3;
  int cs = (lane & 7) ^ r8;                      // XOR-swizzled source chunk
  const uint8_t* gA = A  + (size_t)(row0 + wave*16 + r8) * K + cs*16;
  const uint8_t* gB = Bt + (size_t)(col0 + wave*32 + r8) * K + cs*16;

  int rb = lane & 15;
  int q  = lane >> 4;

  f32x4 acc[2][4];
#pragma unroll
  for (int i = 0; i < 2; i++)
#pragma unroll
    for (int j = 0; j < 4; j++)
      acc[i][j] = (f32x4){0.f, 0.f, 0.f, 0.f};

  auto stage = [&](int k0, uint8_t* As, uint8_t* Bs){
    uint8_t* lA = As + wave*16*128;
    uint8_t* lB = Bs + wave*32*128;
#pragma unroll
    for (int g = 0; g < 2; g++)
      gload16(gA + k0 + (size_t)g*8*K, lA + g*1024);
#pragma unroll
    for (int g = 0; g < 4; g++)
      gload16(gB + k0 + (size_t)g*8*K, lB + g*1024);
  };
  auto compute = [&](const uint8_t* As, const uint8_t* Bs){
    int32x8 a[2], b[4];
#pragma unroll
    for (int mt = 0; mt < 2; mt++){
      int row = wm*32 + mt*16 + rb;
      const uint8_t* base = As + row*128;
      int sw = row & 7;
      int4 lo = *(const int4*)(base + (((2*q)  ^sw)*16));
      int4 hi = *(const int4*)(base + (((2*q+1)^sw)*16));
      int32x8 v; v[0]=lo.x; v[1]=lo.y; v[2]=lo.z; v[3]=lo.w;
                 v[4]=hi.x; v[5]=hi.y; v[6]=hi.z; v[7]=hi.w;
      a[mt] = v;
    }
#pragma unroll
    for (int nt = 0; nt < 4; nt++){
      int row = wn*64 + nt*16 + rb;
      const uint8_t* base = Bs + row*128;
      int sw = row & 7;
      int4 lo = *(const int4*)(base + (((2*q)  ^sw)*16));
      int4 hi = *(const int4*)(base + (((2*q+1)^sw)*16));
      int32x8 v; v[0]=lo.x; v[1]=lo.y; v[2]=lo.z; v[3]=lo.w;
                 v[4]=hi.x; v[5]=hi.y; v[6]=hi.z; v[7]=hi.w;
      b[nt] = v;
    }
#pragma unroll
    for (int mt = 0; mt < 2; mt++)
#pragma unroll
      for (int nt = 0; nt < 4; nt++)
        acc[mt][nt] = __builtin_amdgcn_mfma_scale_f32_16x16x128_f8f6f4(
            a[mt], b[nt], acc[mt][nt], 0, 0, 0, SA_BYTE, 0, SB_BYTE);
  };

  stage(0, As0, Bs0);                  // prologue: window 0 DMA in flight
  int NI = K >> 7;                     // 8 (GEMM1) or 32 (GEMM2), always even
  for (int p = 0; p < NI; p += 2){
    __syncthreads();                   // window p landed (had prior compute to hide)
    if (p+1 < NI) stage((p+1) << 7, As1, Bs1);
    compute(As0, Bs0);
    __syncthreads();                   // window p+1 landed
    if (p+2 < NI) stage((p+2) << 7, As0, Bs0);
    compute(As1, Bs1);
  }

  // LoRA B factors for this lane's 4 columns
  float b0c[4], b1c[4];
#pragma unroll
  for (int nt = 0; nt < 4; nt++){
    int col = col0 + wn*64 + rb + nt*16;
    b0c[nt] = Bl[(e*2+0)*N + col];
    b1c[nt] = Bl[(e*2+1)*N + col];
  }

  if (COMBINE){
    part[tid] = 0.f; part[tid + 256] = 0.f;
    __syncthreads();
  }

#pragma unroll
  for (int mt = 0; mt < 2; mt++){
#pragma unroll
    for (int r = 0; r < 4; r++){
      int row = row0 + wm*32 + mt*16 + q*4 + r;
      float2 u = *(const float2*)(U + row*2);
      float wv = 0.f; int tb = 0;
      if (COMBINE){ wv = wslot[row]; tb = tbat[row]; }
      size_t base = (size_t)row * N + col0 + wn*64 + rb;
#pragma unroll
      for (int nt = 0; nt < 4; nt++){
        float v = acc[mt][nt][r] + LSCALE*(u.x*b0c[nt] + u.y*b1c[nt]);
        if (GELU){
          v = gelu_tanh(v);
          int pk = __builtin_amdgcn_cvt_pk_fp8_f32(8.f*v, 0.f, 0, false);
          Cb[base + nt*16] = (uint8_t)(pk & 0xFF);
        }
        if (COMBINE){
          if (wv != 0.f) atomicAdd(&part[tb*128 + wn*64 + rb + nt*16], wv*v);
        }
      }
    }
  }

  if (COMBINE){
    __syncthreads();
#pragma unroll
    for (int idx = tid; idx < 512; idx += 256){
      float pv = part[idx];
      if (pv != 0.f) atomicAdd(pooled + (size_t)(idx >> 7) * D_MODEL + col0 + (idx & 127), pv);
    }
  }
}

// ---------------- head: out[b][c] = mean_pool . Wh + bh ----------------------
__global__ void head_kernel(const float* __restrict__ pooled, const float* __restrict__ Wh,
                            const float* __restrict__ bh, float* __restrict__ out)
{
  int lane = threadIdx.x & 63;
  int wave = threadIdx.x >> 6;
  int b = wave >> 1, c = wave & 1;
  float s = 0.f;
#pragma unroll
  for (int i = 0; i < 16; i++){
    int d = lane + i*64;
    s += pooled[(size_t)b * D_MODEL + d] * Wh[d*2 + c];
  }
#pragma unroll
  for (int off = 32; off > 0; off >>= 1) s += __shfl_down(s, off);
  if (lane == 0) out[b*2 + c] = s * (1.0f/2048.0f) + bh[c];
}

// ---------------- launch ------------------------------------------------------
extern "C" void kernel_launch(void* const* d_in, const int* in_sizes, int n_in,
                              void* d_out, int out_size, void* d_ws, size_t ws_size,
                              hipStream_t stream)
{
  const float* x  = (const float*)d_in[0];
  const float* Wg = (const float*)d_in[1];
  const float* W1 = (const float*)d_in[2];
  const float* W2 = (const float*)d_in[3];
  const float* A1 = (const float*)d_in[4];
  const float* B1 = (const float*)d_in[5];
  const float* A2 = (const float*)d_in[6];
  const float* B2 = (const float*)d_in[7];
  const float* Wh = (const float*)d_in[8];
  const float* bh = (const float*)d_in[9];
  float* out = (float*)d_out;

  char* p = (char*)d_ws;
  auto alloc = [&](size_t bytes){
    char* r = p;
    p += (bytes + 255) & ~(size_t)255;
    return (void*)r;
  };
  uint8_t* W1q   = (uint8_t*)alloc((size_t)FF_DIM*D_MODEL);     // 4 MB
  uint8_t* W2q   = (uint8_t*)alloc((size_t)D_MODEL*FF_DIM);     // 4 MB
  uint8_t* dispA = (uint8_t*)alloc((size_t)ECAP*D_MODEL);       // 20 MB
  uint8_t* H     = (uint8_t*)alloc((size_t)ECAP*FF_DIM);        // 80 MB
  float* U1       = (float*)alloc((size_t)ECAP*2*4);
  float* U2       = (float*)alloc((size_t)ECAP*2*4);
  float* wslot    = (float*)alloc((size_t)ECAP*4);
  int*   tbat     = (int*)  alloc((size_t)ECAP*4);
  int*   exp_flat = (int*)  alloc((size_t)2*TOK*4);
  float* g_flat   = (float*)alloc((size_t)2*TOK*4);
  int*   slotidx  = (int*)  alloc((size_t)2*TOK*4);
  float* wcomb    = (float*)alloc((size_t)2*TOK*4);
  int*   fillc    = (int*)  alloc(256);
  float* pooled   = (float*)alloc((size_t)4*D_MODEL*4);

  prep_kernel<<<4096, 256, 0, stream>>>(x, Wg, exp_flat, g_flat, pooled, wslot,
                                        W1, W2, W1q, W2q);
  route_all<<<1, 1024, 0, stream>>>(exp_flat, g_flat, slotidx, wcomb, fillc);
  dispatch_kernel<<<2*TOK, 128, 0, stream>>>(x, slotidx, wcomb, dispA, wslot, tbat, A1, U1);
  gemm_mx<true, false><<<dim3(320,32), 256, 0, stream>>>(dispA, W1q, H, D_MODEL, FF_DIM,
                                                         fillc, U1, B1, nullptr, nullptr, nullptr);
  lora_u<<<5120, 256, 0, stream>>>(H, A2, U2, FF_DIM);
  gemm_mx<false, true><<<dim3(320,8), 256, 0, stream>>>(H, W2q, nullptr, FF_DIM, D_MODEL,
                                                        fillc, U2, B2, wslot, tbat, pooled);
  head_kernel<<<1, 512, 0, stream>>>(pooled, Wh, bh, out);
}

// Round 12
// 507.693 us; speedup vs baseline: 2.2205x; 1.1268x over previous
//
#include <hip/hip_runtime.h>
#include <hip/hip_bf16.h>
#include <cstdint>
#include <cstddef>

#define D_MODEL 1024
#define FF_DIM  4096
#define NEXP    8
#define TOK     8192
#define CAP     2560          // ceil(1.25 * 8192*2 / 8)
#define ECAP    (NEXP*CAP)    // 20480
#define LSCALE  2.0f          // lora_alpha / rank = 4/2
#define SA_BYTE 124           // activations stored x8  -> scale 2^-3
#define SB_BYTE 122           // weights stored x32     -> scale 2^-5

typedef __attribute__((ext_vector_type(8))) int   int32x8;
typedef __attribute__((ext_vector_type(4))) float f32x4;
typedef __attribute__((ext_vector_type(2))) float f32x2;

__device__ __forceinline__ void gload16(const void* g, void* l){
  __builtin_amdgcn_global_load_lds((const __attribute__((address_space(1))) void*)g,
                                   (__attribute__((address_space(3))) void*)l, 16, 0, 0);
}
__device__ __forceinline__ float gelu_tanh(float x){
  float u = 0.7978845608028654f * (x + 0.044715f * x * x * x);
  float e = __expf(2.0f * u);
  float t = 1.0f - 2.0f / (e + 1.0f);
  return 0.5f * x * (1.0f + t);
}

// ---- fused prep: blocks 0..2047 = gating (+zero pooled/wslot/Ge), 2048..3071 = quant W1 ----
__global__ void prep_kernel(const float* __restrict__ x, const float* __restrict__ Wg,
                            int* __restrict__ exp_flat, float* __restrict__ g_flat,
                            float* __restrict__ pooled, float* __restrict__ wslot,
                            float* __restrict__ Ge,
                            const float* __restrict__ W1, uint8_t* __restrict__ W1q)
{
  __shared__ float tile[64][65];
  int bx = blockIdx.x;
  int tid = threadIdx.x;
  if (bx < 2048){
    int gid = bx * 256 + tid;
    if (gid < 4*D_MODEL) pooled[gid] = 0.f;
    else if (gid < 4*D_MODEL + ECAP) wslot[gid - 4*D_MODEL] = 0.f;
    else if (gid < 4*D_MODEL + ECAP + 4*NEXP*FF_DIM) Ge[gid - 4*D_MODEL - ECAP] = 0.f;
    int lane = tid & 63;
    int wave = tid >> 6;
    int t = bx * 4 + wave;
    const float4* xv = (const float4*)(x + (size_t)t * D_MODEL);
    float acc[8];
#pragma unroll
    for (int e = 0; e < 8; e++) acc[e] = 0.f;
#pragma unroll
    for (int i = 0; i < 4; i++){
      int i4 = lane + i*64;
      float4 v = xv[i4];
#pragma unroll
      for (int k = 0; k < 4; k++){
        float xs = (&v.x)[k];
        const float4* wr = (const float4*)(Wg + (size_t)(i4*4 + k) * 8);
        float4 w0 = wr[0], w1 = wr[1];
        acc[0] += xs*w0.x; acc[1] += xs*w0.y; acc[2] += xs*w0.z; acc[3] += xs*w0.w;
        acc[4] += xs*w1.x; acc[5] += xs*w1.y; acc[6] += xs*w1.z; acc[7] += xs*w1.w;
      }
    }
#pragma unroll
    for (int off = 32; off > 0; off >>= 1){
#pragma unroll
      for (int e = 0; e < 8; e++) acc[e] += __shfl_down(acc[e], off);
    }
    if (lane == 0){
      float m0 = acc[0]; int e0 = 0;
#pragma unroll
      for (int e = 1; e < 8; e++) if (acc[e] > m0){ m0 = acc[e]; e0 = e; }
      float m1 = -3.4e38f; int e1 = 0;
#pragma unroll
      for (int e = 0; e < 8; e++) if (e != e0 && acc[e] > m1){ m1 = acc[e]; e1 = e; }
      float z = __expf(m1 - m0);
      float inv = 1.f / (1.f + z);
      exp_flat[t]       = e0;
      exp_flat[TOK + t] = e1;
      g_flat[t]         = inv;
      g_flat[TOK + t]   = z * inv;
    }
  } else {
    // quantize+transpose W1 [D][FF] -> W1q [FF][D] fp8 e4m3 (x32)
    int b = bx - 2048;                 // 0..1023
    int d0 = (b & 15) * 64;
    int f0 = (b >> 4) * 64;
    int r  = tid >> 4;
    int c4 = (tid & 15) * 4;
#pragma unroll
    for (int i = 0; i < 4; i++){
      int dl = r + i*16;
      float4 v = *(const float4*)(W1 + (size_t)(d0 + dl) * FF_DIM + f0 + c4);
      tile[dl][c4+0] = v.x; tile[dl][c4+1] = v.y; tile[dl][c4+2] = v.z; tile[dl][c4+3] = v.w;
    }
    __syncthreads();
#pragma unroll
    for (int i = 0; i < 4; i++){
      int fl = r + i*16;
      int f  = f0 + fl;
      int pk = __builtin_amdgcn_cvt_pk_fp8_f32(32.f*tile[c4+0][fl], 32.f*tile[c4+1][fl], 0, false);
      pk     = __builtin_amdgcn_cvt_pk_fp8_f32(32.f*tile[c4+2][fl], 32.f*tile[c4+3][fl], pk, true);
      *(int*)(W1q + (size_t)f * D_MODEL + d0 + c4) = pk;
    }
  }
}

// ------- routing, parallel: exact slot-major cumulative positions ------------
__global__ __launch_bounds__(1024) void route_all(const int* __restrict__ exp_flat,
                                                  const float* __restrict__ g_flat,
                                                  int* __restrict__ slotidx,
                                                  float* __restrict__ wcomb,
                                                  int* __restrict__ fillc)
{
  __shared__ uint8_t rnk[16384];
  __shared__ uint8_t eexp[16384];
  __shared__ int     cnt[256*8];
  __shared__ int     grpoff[64];
  int tid = threadIdx.x;
  int lane = tid & 63, wv = tid >> 6;
  unsigned long long ltmask = (1ull << lane) - 1ull;
  for (int c = wv; c < 256; c += 16){
    int j = c*64 + lane;
    int e = exp_flat[j];
    eexp[j] = (uint8_t)e;
    int r = 0, myc = 0;
#pragma unroll
    for (int q = 0; q < 8; q++){
      unsigned long long m = __ballot(e == q);
      if (e == q) r = __popcll(m & ltmask);
      if (lane == q) myc = __popcll(m);
    }
    rnk[j] = (uint8_t)r;
    if (lane < 8) cnt[c*8 + lane] = myc;
  }
  __syncthreads();
  if (wv == 0){
    int e = lane & 7, g = lane >> 3;
    int run = 0;
    for (int c = g*32; c < g*32 + 32; c++){
      int v = cnt[c*8 + e];
      cnt[c*8 + e] = run;
      run += v;
    }
    int offs = 0, tot = 0;
#pragma unroll
    for (int gg = 0; gg < 8; gg++){
      int v = __shfl(run, gg*8 + e);
      if (gg < g) offs += v;
      tot += v;
    }
    grpoff[lane] = offs;
    if (g == 0) fillc[e] = tot < CAP ? tot : CAP;
  }
  __syncthreads();
  for (int j = tid; j < 16384; j += 1024){
    int e = eexp[j];
    int c = j >> 6;
    int pos = cnt[c*8 + e] + grpoff[(c >> 5)*8 + e] + rnk[j];
    bool keep = pos < CAP;
    slotidx[j] = e*CAP + (keep ? pos : (CAP-1));
    wcomb[j]   = keep ? g_flat[j] : 0.f;
  }
}

// -------- dispatch: scatter tokens -> fp8 buffer (x8) + fused U1 = x.A1 ------
__global__ void dispatch_kernel(const float* __restrict__ x, const int* __restrict__ slotidx,
                                const float* __restrict__ wcomb, uint8_t* __restrict__ dispA,
                                float* __restrict__ wslot, int* __restrict__ tbat,
                                const float* __restrict__ A1, float* __restrict__ U1)
{
  int j = blockIdx.x;
  float w = wcomb[j];
  if (w == 0.f) return;
  int t = j & (TOK - 1);
  int slot = slotidx[j];
  int e = slot / CAP;
  int i = threadIdx.x;
  const float4* src = (const float4*)(x + (size_t)t * D_MODEL);
  float4 a = src[2*i], b = src[2*i+1];
  int p0 = __builtin_amdgcn_cvt_pk_fp8_f32(8.f*a.x, 8.f*a.y, 0, false);
  p0     = __builtin_amdgcn_cvt_pk_fp8_f32(8.f*a.z, 8.f*a.w, p0, true);
  int p1 = __builtin_amdgcn_cvt_pk_fp8_f32(8.f*b.x, 8.f*b.y, 0, false);
  p1     = __builtin_amdgcn_cvt_pk_fp8_f32(8.f*b.z, 8.f*b.w, p1, true);
  int2 o; o.x = p0; o.y = p1;
  *(int2*)(dispA + (size_t)slot * D_MODEL + i*8) = o;
  const float2* Av = (const float2*)(A1 + (size_t)e * D_MODEL * 2);
  int d0 = i*8;
  float xs[8] = {a.x,a.y,a.z,a.w,b.x,b.y,b.z,b.w};
  float pa = 0.f, pb = 0.f;
#pragma unroll
  for (int k = 0; k < 8; k++){
    float2 w2 = Av[d0 + k];
    pa += xs[k]*w2.x; pb += xs[k]*w2.y;
  }
#pragma unroll
  for (int off = 32; off > 0; off >>= 1){
    pa += __shfl_down(pa, off);
    pb += __shfl_down(pb, off);
  }
  __shared__ float red[4];
  int lane = i & 63, wv = i >> 6;
  if (lane == 0){ red[wv*2] = pa; red[wv*2+1] = pb; }
  __syncthreads();
  if (i == 0){
    U1[slot*2+0] = red[0] + red[2];
    U1[slot*2+1] = red[1] + red[3];
    wslot[slot] = w; tbat[slot] = t >> 11;
  }
}

// ------ MX-fp8 GEMM1 (r8 structure, measured best): H = gelu((A/8)(W1q/32)^T + LoRA) ----
__global__ __launch_bounds__(256) void gemm_mx(const uint8_t* __restrict__ A,
                                               const uint8_t* __restrict__ Bt,
                                               uint8_t* __restrict__ Cb,
                                               int K, int N, const int* __restrict__ fillc,
                                               const float* __restrict__ U,
                                               const float* __restrict__ Bl)
{
  int e = blockIdx.x / 20;                       // CAP/128 = 20 row tiles per expert
  if ((blockIdx.x % 20) * 128 >= fillc[e]) return;
  int row0 = blockIdx.x * 128;
  int col0 = blockIdx.y * 128;

  __shared__ __align__(16) uint8_t As[128*128];  // 16 KB
  __shared__ __align__(16) uint8_t Bs[128*128];  // 16 KB

  int tid  = threadIdx.x;
  int lane = tid & 63;
  int wave = tid >> 6;
  int wm = wave & 1, wn = wave >> 1;

  int r8 = lane >> 3;
  int cs = (lane & 7) ^ r8;                      // XOR-swizzled source chunk
  const uint8_t* gA = A  + (size_t)(row0 + wave*32 + r8) * K + cs*16;
  const uint8_t* gB = Bt + (size_t)(col0 + wave*32 + r8) * K + cs*16;
  uint8_t* lA = As + wave*32*128;
  uint8_t* lB = Bs + wave*32*128;

  int rb = lane & 15;
  int q  = lane >> 4;

  f32x4 acc[4][4];
#pragma unroll
  for (int i = 0; i < 4; i++)
#pragma unroll
    for (int j = 0; j < 4; j++)
      acc[i][j] = (f32x4){0.f, 0.f, 0.f, 0.f};

  for (int k0 = 0; k0 < K; k0 += 128){
    __syncthreads();
#pragma unroll
    for (int g = 0; g < 4; g++){
      gload16(gA + k0 + (size_t)g*8*K, lA + g*1024);
      gload16(gB + k0 + (size_t)g*8*K, lB + g*1024);
    }
    __syncthreads();
    int32x8 a[4], b[4];
#pragma unroll
    for (int mt = 0; mt < 4; mt++){
      int row = wm*64 + mt*16 + rb;
      const uint8_t* base = As + row*128;
      int sw = row & 7;
      int4 lo = *(const int4*)(base + (((2*q)  ^sw)*16));
      int4 hi = *(const int4*)(base + (((2*q+1)^sw)*16));
      int32x8 v; v[0]=lo.x; v[1]=lo.y; v[2]=lo.z; v[3]=lo.w;
                 v[4]=hi.x; v[5]=hi.y; v[6]=hi.z; v[7]=hi.w;
      a[mt] = v;
    }
#pragma unroll
    for (int nt = 0; nt < 4; nt++){
      int row = wn*64 + nt*16 + rb;
      const uint8_t* base = Bs + row*128;
      int sw = row & 7;
      int4 lo = *(const int4*)(base + (((2*q)  ^sw)*16));
      int4 hi = *(const int4*)(base + (((2*q+1)^sw)*16));
      int32x8 v; v[0]=lo.x; v[1]=lo.y; v[2]=lo.z; v[3]=lo.w;
                 v[4]=hi.x; v[5]=hi.y; v[6]=hi.z; v[7]=hi.w;
      b[nt] = v;
    }
#pragma unroll
    for (int mt = 0; mt < 4; mt++)
#pragma unroll
      for (int nt = 0; nt < 4; nt++)
        acc[mt][nt] = __builtin_amdgcn_mfma_scale_f32_16x16x128_f8f6f4(
            a[mt], b[nt], acc[mt][nt], 0, 0, 0, SA_BYTE, 0, SB_BYTE);
  }

  float b0c[4], b1c[4];
#pragma unroll
  for (int nt = 0; nt < 4; nt++){
    int col = col0 + wn*64 + rb + nt*16;
    b0c[nt] = Bl[(e*2+0)*N + col];
    b1c[nt] = Bl[(e*2+1)*N + col];
  }

#pragma unroll
  for (int mt = 0; mt < 4; mt++){
#pragma unroll
    for (int r = 0; r < 4; r++){
      int row = row0 + wm*64 + mt*16 + q*4 + r;
      float2 u = *(const float2*)(U + row*2);
      size_t base = (size_t)row * N + col0 + wn*64 + rb;
#pragma unroll
      for (int nt = 0; nt < 4; nt++){
        float v = acc[mt][nt][r] + LSCALE*(u.x*b0c[nt] + u.y*b1c[nt]);
        v = gelu_tanh(v);
        int pk = __builtin_amdgcn_cvt_pk_fp8_f32(8.f*v, 0.f, 0, false);
        Cb[base + nt*16] = (uint8_t)(pk & 0xFF);
      }
    }
  }
}

// ---- Ge reduction: Ge[b][e][f] += w_slot * H[slot][f]  (replaces GEMM2's M dim!) ----
// grid (160 slot-chunks of 128, 8 f-chunks of 512); 256 threads, 2 f per thread.
__global__ void ge_reduce(const uint8_t* __restrict__ H, const float* __restrict__ wslot,
                          const int* __restrict__ tbat, float* __restrict__ Ge)
{
  int sc = blockIdx.x;
  int f0 = blockIdx.y * 512;
  int e  = sc / 20;                    // 20 chunks per expert (CAP/128)
  int tid = threadIdx.x;
  __shared__ float wsl[128];
  __shared__ int   tbl[128];
  if (tid < 128){
    int slot = sc*128 + tid;
    wsl[tid] = wslot[slot] * 0.125f;   // fold fp8 x8 descale
    tbl[tid] = tbat[slot];
  }
  __syncthreads();
  float2 a0 = {0,0}, a1 = {0,0}, a2 = {0,0}, a3 = {0,0};
  const uint8_t* hp = H + (size_t)sc*128*FF_DIM + f0 + tid*2;
  for (int s = 0; s < 128; s++){
    float w = wsl[s];
    if (w != 0.f){                     // uniform branch per slot
      int tb = tbl[s];
      unsigned short raw = *(const unsigned short*)(hp + (size_t)s*FF_DIM);
      f32x2 hv = __builtin_amdgcn_cvt_pk_f32_fp8((int)raw, false);
      float h0 = w*hv.x, h1 = w*hv.y;
      if      (tb == 0){ a0.x += h0; a0.y += h1; }
      else if (tb == 1){ a1.x += h0; a1.y += h1; }
      else if (tb == 2){ a2.x += h0; a2.y += h1; }
      else             { a3.x += h0; a3.y += h1; }
    }
  }
  int f = f0 + tid*2;
  atomicAdd(&Ge[((0*8+e)*FF_DIM) + f],   a0.x); atomicAdd(&Ge[((0*8+e)*FF_DIM) + f+1], a0.y);
  atomicAdd(&Ge[((1*8+e)*FF_DIM) + f],   a1.x); atomicAdd(&Ge[((1*8+e)*FF_DIM) + f+1], a1.y);
  atomicAdd(&Ge[((2*8+e)*FF_DIM) + f],   a2.x); atomicAdd(&Ge[((2*8+e)*FF_DIM) + f+1], a2.y);
  atomicAdd(&Ge[((3*8+e)*FF_DIM) + f],   a3.x); atomicAdd(&Ge[((3*8+e)*FF_DIM) + f+1], a3.y);
}

// ---- collapse: P[b][e][r] = Ge[b][e] . A2_e[:,r];  G[b][f] = sum_e Ge[b][e][f] ----
__global__ void collapse(const float* __restrict__ Ge, const float* __restrict__ A2,
                         float* __restrict__ G, float* __restrict__ P)
{
  int bx = blockIdx.x, tid = threadIdx.x;
  if (bx < 32){
    int b = bx >> 3, e = bx & 7;
    const float*  g  = Ge + (size_t)(b*8+e)*FF_DIM;
    const float2* Av = (const float2*)(A2 + (size_t)e*FF_DIM*2);
    float p0 = 0.f, p1 = 0.f;
    for (int f = tid; f < FF_DIM; f += 256){
      float gv = g[f];
      float2 a = Av[f];
      p0 += gv*a.x; p1 += gv*a.y;
    }
#pragma unroll
    for (int off = 32; off > 0; off >>= 1){
      p0 += __shfl_down(p0, off);
      p1 += __shfl_down(p1, off);
    }
    __shared__ float red[8];
    int lane = tid & 63, wv = tid >> 6;
    if (lane == 0){ red[wv*2] = p0; red[wv*2+1] = p1; }
    __syncthreads();
    if (tid == 0){
      P[(b*8+e)*2+0] = red[0]+red[2]+red[4]+red[6];
      P[(b*8+e)*2+1] = red[1]+red[3]+red[5]+red[7];
    }
  } else {
    for (int c = (bx-32)*1024 + tid; c < (bx-31)*1024; c += 256){
      int b = c >> 12, f = c & 4095;
      float s = 0.f;
#pragma unroll
      for (int e = 0; e < 8; e++) s += Ge[(size_t)(b*8+e)*FF_DIM + f];
      G[b*FF_DIM + f] = s;
    }
  }
}

// ---- final pool: pooled[b][d] = G[b].W2[:,d] + LSCALE*sum_e P[b][e].B2_e[:,d] ----
// grid 64: b = bx>>4; fq = (bx&15)>>2 (K quarter); db = bx&3 (d quarter)
__global__ void final_pool(const float* __restrict__ G, const float* __restrict__ W2,
                           const float* __restrict__ P, const float* __restrict__ B2,
                           float* __restrict__ pooled)
{
  int bx = blockIdx.x, tid = threadIdx.x;
  int b  = bx >> 4;
  int r  = bx & 15;
  int fq = r >> 2, db = r & 3;
  int d  = db*256 + tid;
  const float* g = G  + (size_t)b*FF_DIM + fq*1024;
  const float* w = W2 + (size_t)fq*1024*D_MODEL + d;
  float acc = 0.f;
#pragma unroll 4
  for (int f = 0; f < 1024; f++) acc += g[f] * w[(size_t)f*D_MODEL];
  if (fq == 0){
    float lt = 0.f;
#pragma unroll
    for (int e = 0; e < 8; e++){
      lt += P[(b*8+e)*2+0]*B2[(e*2+0)*D_MODEL + d]
          + P[(b*8+e)*2+1]*B2[(e*2+1)*D_MODEL + d];
    }
    acc += LSCALE*lt;
  }
  atomicAdd(&pooled[b*D_MODEL + d], acc);
}

// ---------------- head: out[b][c] = mean_pool . Wh + bh ----------------------
__global__ void head_kernel(const float* __restrict__ pooled, const float* __restrict__ Wh,
                            const float* __restrict__ bh, float* __restrict__ out)
{
  int lane = threadIdx.x & 63;
  int wave = threadIdx.x >> 6;
  int b = wave >> 1, c = wave & 1;
  float s = 0.f;
#pragma unroll
  for (int i = 0; i < 16; i++){
    int d = lane + i*64;
    s += pooled[(size_t)b * D_MODEL + d] * Wh[d*2 + c];
  }
#pragma unroll
  for (int off = 32; off > 0; off >>= 1) s += __shfl_down(s, off);
  if (lane == 0) out[b*2 + c] = s * (1.0f/2048.0f) + bh[c];
}

// ---------------- launch ------------------------------------------------------
extern "C" void kernel_launch(void* const* d_in, const int* in_sizes, int n_in,
                              void* d_out, int out_size, void* d_ws, size_t ws_size,
                              hipStream_t stream)
{
  const float* x  = (const float*)d_in[0];
  const float* Wg = (const float*)d_in[1];
  const float* W1 = (const float*)d_in[2];
  const float* W2 = (const float*)d_in[3];
  const float* A1 = (const float*)d_in[4];
  const float* B1 = (const float*)d_in[5];
  const float* A2 = (const float*)d_in[6];
  const float* B2 = (const float*)d_in[7];
  const float* Wh = (const float*)d_in[8];
  const float* bh = (const float*)d_in[9];
  float* out = (float*)d_out;

  char* p = (char*)d_ws;
  auto alloc = [&](size_t bytes){
    char* r = p;
    p += (bytes + 255) & ~(size_t)255;
    return (void*)r;
  };
  uint8_t* W1q   = (uint8_t*)alloc((size_t)FF_DIM*D_MODEL);     // 4 MB
  uint8_t* dispA = (uint8_t*)alloc((size_t)ECAP*D_MODEL);       // 20 MB
  uint8_t* H     = (uint8_t*)alloc((size_t)ECAP*FF_DIM);        // 80 MB
  float* U1       = (float*)alloc((size_t)ECAP*2*4);
  float* wslot    = (float*)alloc((size_t)ECAP*4);
  int*   tbat     = (int*)  alloc((size_t)ECAP*4);
  int*   exp_flat = (int*)  alloc((size_t)2*TOK*4);
  float* g_flat   = (float*)alloc((size_t)2*TOK*4);
  int*   slotidx  = (int*)  alloc((size_t)2*TOK*4);
  float* wcomb    = (float*)alloc((size_t)2*TOK*4);
  int*   fillc    = (int*)  alloc(256);
  float* pooled   = (float*)alloc((size_t)4*D_MODEL*4);
  float* Ge       = (float*)alloc((size_t)4*NEXP*FF_DIM*4);     // 512 KB
  float* G        = (float*)alloc((size_t)4*FF_DIM*4);          // 64 KB
  float* P        = (float*)alloc((size_t)4*NEXP*2*4);

  prep_kernel<<<3072, 256, 0, stream>>>(x, Wg, exp_flat, g_flat, pooled, wslot, Ge, W1, W1q);
  route_all<<<1, 1024, 0, stream>>>(exp_flat, g_flat, slotidx, wcomb, fillc);
  dispatch_kernel<<<2*TOK, 128, 0, stream>>>(x, slotidx, wcomb, dispA, wslot, tbat, A1, U1);
  gemm_mx<<<dim3(160,32), 256, 0, stream>>>(dispA, W1q, H, D_MODEL, FF_DIM, fillc, U1, B1);
  ge_reduce<<<dim3(160,8), 256, 0, stream>>>(H, wslot, tbat, Ge);
  collapse<<<48, 256, 0, stream>>>(Ge, A2, G, P);
  final_pool<<<64, 256, 0, stream>>>(G, W2, P, B2, pooled);
  head_kernel<<<1, 512, 0, stream>>>(pooled, Wh, bh, out);
}